// Round 12
// baseline (507.342 us; speedup 1.0000x reference)
//
#include <hip/hip_runtime.h>
#include <hip/hip_bf16.h>
#include <hip/hip_cooperative_groups.h>

namespace cg = cooperative_groups;

#define C 64
#define COOP_BLOCKS 1024

// bf16 helpers (manual RNE pack / cheap unpack)
__device__ __forceinline__ float bflo(unsigned u) { return __uint_as_float(u << 16); }
__device__ __forceinline__ float bfhi(unsigned u) { return __uint_as_float(u & 0xffff0000u); }
__device__ __forceinline__ unsigned bfrne(float f) {
    unsigned u = __float_as_uint(f);
    return (u + 0x7fffu + ((u >> 16) & 1u)) >> 16;
}

// hwreg(HW_REG_XCC_ID=20, offset=0, width=4) -> simm16 = 20 | (4-1)<<11 = 6164
__device__ __forceinline__ unsigned xcc_id() {
    return __builtin_amdgcn_s_getreg(6164) & 7u;
}

// ---- fused graph build: zero + per-XCD histogram + scan + bucket ----
// R9-11 lesson: shaving individual sub-41us kernels stopped moving the wall
// clock (total flat at ~131us across 3 rounds) -> per-dispatch overhead /
// serialization across 7 launches is a first-order cost. Fuse the 5 build
// stages into one cooperative kernel with grid.sync() phase barriers.
// __launch_bounds__(256,8): <=64 VGPR -> 8 blocks/CU capacity >= 1024 grid.
__global__ void __launch_bounds__(256, 8)
build_kernel(const int* __restrict__ dst, const int* __restrict__ src,
             unsigned* __restrict__ part, int S,
             unsigned* __restrict__ rank,
             unsigned* __restrict__ deg, unsigned* __restrict__ offs,
             unsigned* __restrict__ bsum, float* __restrict__ dis,
             unsigned* __restrict__ ssrc, int N, int E) {
    cg::grid_group grid = cg::this_grid();
    __shared__ unsigned s[256];
    int t    = threadIdx.x;
    int gtid = blockIdx.x * 256 + t;
    int gsz  = gridDim.x * 256;

    // --- phase 0: zero the 8 partial histograms (8*S u32 = 2*S uint4) ---
    int n4 = 2 * S;
    for (int i = gtid; i < n4; i += gsz) {
        ((uint4*)part)[i] = make_uint4(0u, 0u, 0u, 0u);
    }
    grid.sync();

    // --- phase 1: per-XCD degree histogram over dst + per-edge local rank ---
    // Workgroup-scope atomic -> no sc1 -> RMW in this XCD's L2 (all blocks on
    // one XCD share that L2; partials keyed by physical XCC_ID).
    {
        unsigned x = xcc_id();
        for (int e = gtid; e < E; e += gsz) {
            unsigned d = (unsigned)dst[e];
            unsigned r = __hip_atomic_fetch_add(&part[x * (unsigned)S + d], 1u,
                                                __ATOMIC_RELAXED, __HIP_MEMORY_SCOPE_WORKGROUP);
            rank[e] = (x << 27) | r;
        }
    }
    grid.sync();

    // --- phase 2: per-1024-chunk scan: deg = sum partials; part <- cross-xcd
    //     exclusive prefix; dis = rsqrt(deg+1); chunk-local exclusive offs; bsum ---
    int nchunks = (N + 1023) >> 10;
    for (int c = blockIdx.x; c < nchunks; c += gridDim.x) {
        int base = c * 1024 + t * 4;
        unsigned v0 = 0, v1 = 0, v2 = 0, v3 = 0;
        if (base + 4 <= N) {
            uint4 run = make_uint4(0u, 0u, 0u, 0u);
            #pragma unroll
            for (int x = 0; x < 8; ++x) {
                uint4* p = (uint4*)&part[(size_t)x * S + base];
                uint4 v = *p;
                *p = run;                 // exclusive prefix for this xcd
                run.x += v.x; run.y += v.y; run.z += v.z; run.w += v.w;
            }
            v0 = run.x; v1 = run.y; v2 = run.z; v3 = run.w;
            *(uint4*)&deg[base] = run;
            dis[base + 0] = rsqrtf((float)(v0 + 1u));
            dis[base + 1] = rsqrtf((float)(v1 + 1u));
            dis[base + 2] = rsqrtf((float)(v2 + 1u));
            dis[base + 3] = rsqrtf((float)(v3 + 1u));
        } else if (base < N) {
            for (int j = 0; j < 4; ++j) {
                int i = base + j;
                if (i >= N) break;
                unsigned run = 0;
                #pragma unroll
                for (int x = 0; x < 8; ++x) {
                    unsigned* p = &part[(size_t)x * S + i];
                    unsigned v = *p;
                    *p = run;
                    run += v;
                }
                deg[i] = run;
                dis[i] = rsqrtf((float)(run + 1u));
                if (j == 0) v0 = run; else if (j == 1) v1 = run;
                else if (j == 2) v2 = run; else v3 = run;
            }
        }
        s[t] = v0 + v1 + v2 + v3;
        __syncthreads();
        for (int d = 1; d < 256; d <<= 1) {
            unsigned val = (t >= d) ? s[t - d] : 0u;
            __syncthreads();
            s[t] += val;
            __syncthreads();
        }
        unsigned excl = (t == 0) ? 0u : s[t - 1];
        if (t == 255) bsum[c] = s[255];
        if (base + 0 < N) offs[base + 0] = excl;
        if (base + 1 < N) offs[base + 1] = excl + v0;
        if (base + 2 < N) offs[base + 2] = excl + v0 + v1;
        if (base + 3 < N) offs[base + 3] = excl + v0 + v1 + v2;
        __syncthreads();
    }
    grid.sync();

    // --- phase 3: exclusive scan of bsum (block 0; nchunks <= 256) ---
    if (blockIdx.x == 0) {
        s[t] = (t < nchunks) ? bsum[t] : 0u;
        __syncthreads();
        for (int d = 1; d < 256; d <<= 1) {
            unsigned val = (t >= d) ? s[t - d] : 0u;
            __syncthreads();
            s[t] += val;
            __syncthreads();
        }
        if (t < nchunks) bsum[t] = (t == 0) ? 0u : s[t - 1];
    }
    grid.sync();

    // --- phase 4: bucket edges by dst (atomic-free via packed xcd/rank) ---
    for (int e = gtid; e < E; e += gsz) {
        unsigned d = (unsigned)dst[e];
        unsigned u = rank[e];
        unsigned x = u >> 27;
        unsigned pos = offs[d] + bsum[d >> 10] + part[(size_t)x * S + d] + (u & 0x07FFFFFFu);
        ssrc[pos] = (unsigned)src[e];
    }
}

// ---- hs(bf16) = dis[row] * (x @ W): LDS-tiled, 4x4 register micro-tile ----
// __launch_bounds__(256,4): cap 128 VGPRs (default build chose 232 -> 8.9%
// occupancy, latency-bound). unroll 2 keeps live ranges small.
__global__ void __launch_bounds__(256, 4)
gemm64_kernel(const float* __restrict__ x, const float* __restrict__ W,
              const float* __restrict__ dis, unsigned short* __restrict__ hsb, int n) {
    __shared__ float Xl[64][68];
    __shared__ float Wl[64][64];
    int tid = threadIdx.x;
    int rbase = blockIdx.x * 64;
    for (int i = tid; i < 1024; i += 256) {
        ((float4*)Wl)[i] = ((const float4*)W)[i];
    }
    for (int i = tid; i < 1024; i += 256) {
        int r = i >> 4, kq = i & 15;
        float4 v;
        if (rbase + r < n) v = ((const float4*)(x + (size_t)(rbase + r) * C))[kq];
        else               v = make_float4(0.f, 0.f, 0.f, 0.f);
        *(float4*)&Xl[r][kq * 4] = v;
    }
    __syncthreads();

    int tx = tid & 15;      // channel group: channels 4tx..4tx+3
    int ty = tid >> 4;      // row group: rows 4ty..4ty+3
    float4 acc[4];
    #pragma unroll
    for (int j = 0; j < 4; ++j) acc[j] = make_float4(0.f, 0.f, 0.f, 0.f);

    #pragma unroll 2
    for (int kb = 0; kb < 16; ++kb) {
        float4 wv0 = *(const float4*)&Wl[kb * 4 + 0][tx * 4];
        float4 wv1 = *(const float4*)&Wl[kb * 4 + 1][tx * 4];
        float4 wv2 = *(const float4*)&Wl[kb * 4 + 2][tx * 4];
        float4 wv3 = *(const float4*)&Wl[kb * 4 + 3][tx * 4];
        #pragma unroll
        for (int j = 0; j < 4; ++j) {
            float4 xv = *(const float4*)&Xl[ty * 4 + j][kb * 4];
            acc[j].x = fmaf(xv.x, wv0.x, acc[j].x);
            acc[j].y = fmaf(xv.x, wv0.y, acc[j].y);
            acc[j].z = fmaf(xv.x, wv0.z, acc[j].z);
            acc[j].w = fmaf(xv.x, wv0.w, acc[j].w);
            acc[j].x = fmaf(xv.y, wv1.x, acc[j].x);
            acc[j].y = fmaf(xv.y, wv1.y, acc[j].y);
            acc[j].z = fmaf(xv.y, wv1.z, acc[j].z);
            acc[j].w = fmaf(xv.y, wv1.w, acc[j].w);
            acc[j].x = fmaf(xv.z, wv2.x, acc[j].x);
            acc[j].y = fmaf(xv.z, wv2.y, acc[j].y);
            acc[j].z = fmaf(xv.z, wv2.z, acc[j].z);
            acc[j].w = fmaf(xv.z, wv2.w, acc[j].w);
            acc[j].x = fmaf(xv.w, wv3.x, acc[j].x);
            acc[j].y = fmaf(xv.w, wv3.y, acc[j].y);
            acc[j].z = fmaf(xv.w, wv3.z, acc[j].z);
            acc[j].w = fmaf(xv.w, wv3.w, acc[j].w);
        }
    }
    #pragma unroll
    for (int j = 0; j < 4; ++j) {
        int row = rbase + ty * 4 + j;
        if (row < n) {
            float d = dis[row];
            unsigned p0 = bfrne(acc[j].x * d) | (bfrne(acc[j].y * d) << 16);
            unsigned p1 = bfrne(acc[j].z * d) | (bfrne(acc[j].w * d) << 16);
            ((uint2*)(hsb + (size_t)row * C))[tx] = make_uint2(p0, p1);
        }
    }
}

// ---- gather: one wave per node; 8 edge-groups x 8 lanes (uint4 = 8 bf16 each) ----
__global__ void gather_kernel(const unsigned* __restrict__ offs, const unsigned* __restrict__ bsum,
                              const unsigned* __restrict__ deg, const unsigned* __restrict__ ssrc,
                              const float* __restrict__ dis, const unsigned short* __restrict__ hsb,
                              const float* __restrict__ b, float* __restrict__ out, int n) {
    int node = blockIdx.x * 4 + (threadIdx.x >> 6);
    if (node >= n) return;
    int lane = threadIdx.x & 63;
    int g = lane >> 3;          // edge group 0..7
    int l = lane & 7;           // uint4 slot within 128B row (channels 8l..8l+7)
    unsigned off = offs[node] + bsum[node >> 10];
    unsigned dg  = deg[node];
    float a0 = 0.f, a1 = 0.f, a2 = 0.f, a3 = 0.f, a4 = 0.f, a5 = 0.f, a6 = 0.f, a7 = 0.f;
    unsigned k = 0;
    for (; k + 16 <= dg; k += 16) {
        unsigned s0 = ssrc[off + k + g];
        unsigned s1 = ssrc[off + k + 8 + g];
        uint4 v0 = ((const uint4*)(hsb + (size_t)s0 * C))[l];
        uint4 v1 = ((const uint4*)(hsb + (size_t)s1 * C))[l];
        a0 += bflo(v0.x) + bflo(v1.x); a1 += bfhi(v0.x) + bfhi(v1.x);
        a2 += bflo(v0.y) + bflo(v1.y); a3 += bfhi(v0.y) + bfhi(v1.y);
        a4 += bflo(v0.z) + bflo(v1.z); a5 += bfhi(v0.z) + bfhi(v1.z);
        a6 += bflo(v0.w) + bflo(v1.w); a7 += bfhi(v0.w) + bfhi(v1.w);
    }
    if (k + 8 <= dg) {
        unsigned s0 = ssrc[off + k + g];
        uint4 v0 = ((const uint4*)(hsb + (size_t)s0 * C))[l];
        a0 += bflo(v0.x); a1 += bfhi(v0.x);
        a2 += bflo(v0.y); a3 += bfhi(v0.y);
        a4 += bflo(v0.z); a5 += bfhi(v0.z);
        a6 += bflo(v0.w); a7 += bfhi(v0.w);
        k += 8;
    }
    if (k + g < dg) {
        unsigned s0 = ssrc[off + k + g];
        uint4 v0 = ((const uint4*)(hsb + (size_t)s0 * C))[l];
        a0 += bflo(v0.x); a1 += bfhi(v0.x);
        a2 += bflo(v0.y); a3 += bfhi(v0.y);
        a4 += bflo(v0.z); a5 += bfhi(v0.z);
        a6 += bflo(v0.w); a7 += bfhi(v0.w);
    }
    // reduce across the 8 edge groups (xor 8, 16, 32)
    #pragma unroll
    for (int m = 8; m <= 32; m <<= 1) {
        a0 += __shfl_xor(a0, m); a1 += __shfl_xor(a1, m);
        a2 += __shfl_xor(a2, m); a3 += __shfl_xor(a3, m);
        a4 += __shfl_xor(a4, m); a5 += __shfl_xor(a5, m);
        a6 += __shfl_xor(a6, m); a7 += __shfl_xor(a7, m);
    }
    // groups 0/1 write the two float4 halves of the row
    if (g < 2) {
        float di = dis[node];
        uint4 u = ((const uint4*)(hsb + (size_t)node * C))[l];
        unsigned w0 = (g == 0) ? u.x : u.z;
        unsigned w1 = (g == 0) ? u.y : u.w;
        float s0 = bflo(w0), s1 = bfhi(w0), s2 = bflo(w1), s3 = bfhi(w1);
        float e0 = (g == 0) ? a0 : a4;
        float e1 = (g == 0) ? a1 : a5;
        float e2 = (g == 0) ? a2 : a6;
        float e3 = (g == 0) ? a3 : a7;
        float4 bv = ((const float4*)b)[l * 2 + g];
        float4 o;
        o.x = di * (s0 + e0) + bv.x;
        o.y = di * (s1 + e1) + bv.y;
        o.z = di * (s2 + e2) + bv.z;
        o.w = di * (s3 + e3) + bv.w;
        ((float4*)(out + (size_t)node * C))[l * 2 + g] = o;
    }
}

extern "C" void kernel_launch(void* const* d_in, const int* in_sizes, int n_in,
                              void* d_out, int out_size, void* d_ws, size_t ws_size,
                              hipStream_t stream) {
    const float* x   = (const float*)d_in[0];
    const int*   ei  = (const int*)d_in[1];   // [2, E]: src = ei[e], dst = ei[E+e]
    const float* W   = (const float*)d_in[2];
    const float* b   = (const float*)d_in[3];
    float*       out = (float*)d_out;

    const int N = in_sizes[0] / C;
    const int E = in_sizes[1] / 2;
    const int* src = ei;
    const int* dst = ei + E;

    const int S = (N + 63) & ~63;   // per-XCD partial stride (16B-aligned uint4 rows)

    // workspace layout (256B aligned slots)
    char* ws = (char*)d_ws;
    size_t o = 0;
    auto carve = [&](size_t bytes) { char* p = ws + o; o = (o + bytes + 255) & ~(size_t)255; return p; };
    unsigned* part      = (unsigned*)carve((size_t)8 * S * 4);
    unsigned* deg       = (unsigned*)carve((size_t)N * 4);
    unsigned* offs      = (unsigned*)carve((size_t)N * 4);
    unsigned* bsum      = (unsigned*)carve(1024 * 4);
    float*    dis       = (float*)carve((size_t)N * 4);
    unsigned* rank      = (unsigned*)carve((size_t)E * 4);
    unsigned* ssrc      = (unsigned*)carve((size_t)E * 4);
    unsigned short* hsb = (unsigned short*)carve((size_t)N * C * 2);

    // fused build: zero + count + scan + bucket (one cooperative dispatch)
    {
        const int*  dst_a  = dst;
        const int*  src_a  = src;
        unsigned*   part_a = part;
        int         S_a    = S;
        unsigned*   rank_a = rank;
        unsigned*   deg_a  = deg;
        unsigned*   offs_a = offs;
        unsigned*   bsum_a = bsum;
        float*      dis_a  = dis;
        unsigned*   ssrc_a = ssrc;
        int         N_a    = N;
        int         E_a    = E;
        void* args[] = { &dst_a, &src_a, &part_a, &S_a, &rank_a, &deg_a,
                         &offs_a, &bsum_a, &dis_a, &ssrc_a, &N_a, &E_a };
        hipLaunchCooperativeKernel((const void*)build_kernel,
                                   dim3(COOP_BLOCKS), dim3(256), args, 0, stream);
    }

    // hs = dis * (x @ W), bf16
    gemm64_kernel<<<(N + 63) / 64, 256, 0, stream>>>(x, W, dis, hsb, N);

    // gather + self loop + bias
    gather_kernel<<<(N + 3) / 4, 256, 0, stream>>>(offs, bsum, deg, ssrc, dis, hsb, b, out, N);
}

// Round 13
// 148.149 us; speedup vs baseline: 3.4245x; 3.4245x over previous
//
#include <hip/hip_runtime.h>
#include <hip/hip_bf16.h>

#define C 64

// bf16 helpers (manual RNE pack / cheap unpack)
__device__ __forceinline__ float bflo(unsigned u) { return __uint_as_float(u << 16); }
__device__ __forceinline__ float bfhi(unsigned u) { return __uint_as_float(u & 0xffff0000u); }
__device__ __forceinline__ unsigned bfrne(float f) {
    unsigned u = __float_as_uint(f);
    return (u + 0x7fffu + ((u >> 16) & 1u)) >> 16;
}

// hwreg(HW_REG_XCC_ID=20, offset=0, width=4) -> simm16 = 20 | (4-1)<<11 = 6164
__device__ __forceinline__ unsigned xcc_id() {
    return __builtin_amdgcn_s_getreg(6164) & 7u;
}

// ---- K1: zero the 8 per-XCD partial histograms ----
__global__ void zero_kernel(uint4* __restrict__ p, int n4) {
    int i = blockIdx.x * blockDim.x + threadIdx.x;
    if (i < n4) p[i] = make_uint4(0u, 0u, 0u, 0u);
}

// ---- K2: per-XCD degree histogram; 4 edges/thread (uint4 dst load, uint4 rank store) ----
// Workgroup-scope atomic -> no sc1 -> RMW stays in the issuing XCD's L2.
__global__ void count_part_kernel(const int* __restrict__ dst, unsigned* __restrict__ part,
                                  int S, unsigned* __restrict__ rank, int E) {
    int g = blockIdx.x * blockDim.x + threadIdx.x;
    int e0 = g * 4;
    if (e0 >= E) return;
    unsigned x = xcc_id();
    unsigned xbase = x * (unsigned)S;
    if (e0 + 4 <= E) {
        uint4 d4 = ((const uint4*)dst)[g];
        uint4 r4;
        r4.x = (x << 27) | __hip_atomic_fetch_add(&part[xbase + d4.x], 1u, __ATOMIC_RELAXED, __HIP_MEMORY_SCOPE_WORKGROUP);
        r4.y = (x << 27) | __hip_atomic_fetch_add(&part[xbase + d4.y], 1u, __ATOMIC_RELAXED, __HIP_MEMORY_SCOPE_WORKGROUP);
        r4.z = (x << 27) | __hip_atomic_fetch_add(&part[xbase + d4.z], 1u, __ATOMIC_RELAXED, __HIP_MEMORY_SCOPE_WORKGROUP);
        r4.w = (x << 27) | __hip_atomic_fetch_add(&part[xbase + d4.w], 1u, __ATOMIC_RELAXED, __HIP_MEMORY_SCOPE_WORKGROUP);
        ((uint4*)rank)[g] = r4;
    } else {
        for (int e = e0; e < E; ++e) {
            unsigned d = (unsigned)dst[e];
            unsigned r = __hip_atomic_fetch_add(&part[xbase + d], 1u, __ATOMIC_RELAXED, __HIP_MEMORY_SCOPE_WORKGROUP);
            rank[e] = (x << 27) | r;
        }
    }
}

// ---- K3: fused per-chunk scan + gemm (chunk = 256 nodes, 4 tiles of 64 rows) ----
// Phase A: deg = sum of 8 partials (part <- cross-xcd exclusive prefix);
//          dis = rsqrt(deg+1) (kept in LDS); chunk-local exclusive offs; bsum[c].
// Phase B: hs(bf16) = dis * (x @ W) for the same 256 rows; W staged ONCE per
//          block (4x amortization vs per-64-row blocks). All intra-block deps.
__global__ void __launch_bounds__(256, 4)
scan_gemm_kernel(unsigned* __restrict__ part, int S,
                 const float* __restrict__ x, const float* __restrict__ W,
                 unsigned* __restrict__ deg, unsigned* __restrict__ offs,
                 unsigned* __restrict__ bsum, float* __restrict__ dis,
                 unsigned short* __restrict__ hsb, int N) {
    __shared__ float Wl[64][64];
    __shared__ float Xl[64][68];
    __shared__ unsigned s[256];
    __shared__ float sdis[256];
    int t = threadIdx.x;
    int nbase = blockIdx.x * 256;

    // stage W (once per block)
    for (int i = t; i < 1024; i += 256) {
        ((float4*)Wl)[i] = ((const float4*)W)[i];
    }

    // --- phase A: one node per thread ---
    int i = nbase + t;
    unsigned degv = 0;
    if (i < N) {
        unsigned run = 0;
        #pragma unroll
        for (int xx = 0; xx < 8; ++xx) {
            unsigned* p = &part[(size_t)xx * S + i];
            unsigned v = *p;
            *p = run;                 // exclusive prefix across xcds
            run += v;
        }
        degv = run;
        deg[i] = run;
        float dv = rsqrtf((float)(run + 1u));
        dis[i] = dv;
        sdis[t] = dv;
    } else {
        sdis[t] = 0.f;
    }
    s[t] = degv;
    __syncthreads();
    for (int d = 1; d < 256; d <<= 1) {
        unsigned v = (t >= d) ? s[t - d] : 0u;
        __syncthreads();
        s[t] += v;
        __syncthreads();
    }
    if (i < N) offs[i] = s[t] - degv;      // inclusive - own = exclusive
    if (t == 255) bsum[blockIdx.x] = s[255];
    __syncthreads();

    // --- phase B: 4 gemm tiles of 64 rows ---
    int tx = t & 15;      // channel group
    int ty = t >> 4;      // row group
    for (int tile = 0; tile < 4; ++tile) {
        int rbase = nbase + tile * 64;
        if (rbase >= N) break;            // block-uniform
        for (int ii = t; ii < 1024; ii += 256) {
            int r = ii >> 4, kq = ii & 15;
            float4 v;
            if (rbase + r < N) v = ((const float4*)(x + (size_t)(rbase + r) * C))[kq];
            else               v = make_float4(0.f, 0.f, 0.f, 0.f);
            *(float4*)&Xl[r][kq * 4] = v;
        }
        __syncthreads();
        float4 acc[4];
        #pragma unroll
        for (int j = 0; j < 4; ++j) acc[j] = make_float4(0.f, 0.f, 0.f, 0.f);
        #pragma unroll 2
        for (int kb = 0; kb < 16; ++kb) {
            float4 wv0 = *(const float4*)&Wl[kb * 4 + 0][tx * 4];
            float4 wv1 = *(const float4*)&Wl[kb * 4 + 1][tx * 4];
            float4 wv2 = *(const float4*)&Wl[kb * 4 + 2][tx * 4];
            float4 wv3 = *(const float4*)&Wl[kb * 4 + 3][tx * 4];
            #pragma unroll
            for (int j = 0; j < 4; ++j) {
                float4 xv = *(const float4*)&Xl[ty * 4 + j][kb * 4];
                acc[j].x = fmaf(xv.x, wv0.x, acc[j].x);
                acc[j].y = fmaf(xv.x, wv0.y, acc[j].y);
                acc[j].z = fmaf(xv.x, wv0.z, acc[j].z);
                acc[j].w = fmaf(xv.x, wv0.w, acc[j].w);
                acc[j].x = fmaf(xv.y, wv1.x, acc[j].x);
                acc[j].y = fmaf(xv.y, wv1.y, acc[j].y);
                acc[j].z = fmaf(xv.y, wv1.z, acc[j].z);
                acc[j].w = fmaf(xv.y, wv1.w, acc[j].w);
                acc[j].x = fmaf(xv.z, wv2.x, acc[j].x);
                acc[j].y = fmaf(xv.z, wv2.y, acc[j].y);
                acc[j].z = fmaf(xv.z, wv2.z, acc[j].z);
                acc[j].w = fmaf(xv.z, wv2.w, acc[j].w);
                acc[j].x = fmaf(xv.w, wv3.x, acc[j].x);
                acc[j].y = fmaf(xv.w, wv3.y, acc[j].y);
                acc[j].z = fmaf(xv.w, wv3.z, acc[j].z);
                acc[j].w = fmaf(xv.w, wv3.w, acc[j].w);
            }
        }
        #pragma unroll
        for (int j = 0; j < 4; ++j) {
            int row = rbase + ty * 4 + j;
            if (row < N) {
                float d = sdis[tile * 64 + ty * 4 + j];
                unsigned p0 = bfrne(acc[j].x * d) | (bfrne(acc[j].y * d) << 16);
                unsigned p1 = bfrne(acc[j].z * d) | (bfrne(acc[j].w * d) << 16);
                ((uint2*)(hsb + (size_t)row * C))[tx] = make_uint2(p0, p1);
            }
        }
        __syncthreads();   // before next tile overwrites Xl
    }
}

// ---- K4: bucket edges; per-block replicated LDS scan of bsum (replaces scan2) ----
__global__ void __launch_bounds__(256)
bucket_kernel(const int* __restrict__ src, const int* __restrict__ dst,
              const unsigned* __restrict__ offs, const unsigned* __restrict__ bsum,
              const unsigned* __restrict__ part, int S,
              const unsigned* __restrict__ rank, unsigned* __restrict__ ssrc,
              int E, int nch) {
    __shared__ unsigned sb[512];
    int t = threadIdx.x;
    sb[t]       = (t < nch)       ? bsum[t]       : 0u;
    sb[t + 256] = (t + 256 < nch) ? bsum[t + 256] : 0u;
    __syncthreads();
    for (int d = 1; d < 512; d <<= 1) {
        unsigned v0 = (t >= d) ? sb[t - d] : 0u;
        unsigned v1 = sb[t + 256 - d];
        __syncthreads();
        sb[t] += v0;
        sb[t + 256] += v1;
        __syncthreads();
    }
    // sb = inclusive scan; prefix(c) = c ? sb[c-1] : 0
    int g = blockIdx.x * 256 + t;
    int e0 = g * 4;
    if (e0 >= E) return;
    if (e0 + 4 <= E) {
        uint4 d4 = ((const uint4*)dst)[g];
        uint4 s4 = ((const uint4*)src)[g];
        uint4 r4 = ((const uint4*)rank)[g];
        #define PLACE(dd, ss, uu) { \
            unsigned ch = (dd) >> 8; \
            unsigned pre = ch ? sb[ch - 1] : 0u; \
            unsigned xx = (uu) >> 27; \
            unsigned pos = offs[dd] + pre + part[(size_t)xx * S + (dd)] + ((uu) & 0x07FFFFFFu); \
            ssrc[pos] = (ss); }
        PLACE(d4.x, s4.x, r4.x);
        PLACE(d4.y, s4.y, r4.y);
        PLACE(d4.z, s4.z, r4.z);
        PLACE(d4.w, s4.w, r4.w);
        #undef PLACE
    } else {
        for (int e = e0; e < E; ++e) {
            unsigned dd = (unsigned)dst[e];
            unsigned uu = rank[e];
            unsigned ch = dd >> 8;
            unsigned pre = ch ? sb[ch - 1] : 0u;
            unsigned xx = uu >> 27;
            unsigned pos = offs[dd] + pre + part[(size_t)xx * S + dd] + (uu & 0x07FFFFFFu);
            ssrc[pos] = (unsigned)src[e];
        }
    }
}

// ---- K5: gather; per-block bsum prefix sum (4 nodes/block never straddle a chunk) ----
__global__ void gather_kernel(const unsigned* __restrict__ offs, const unsigned* __restrict__ bsum,
                              const unsigned* __restrict__ deg, const unsigned* __restrict__ ssrc,
                              const float* __restrict__ dis, const unsigned short* __restrict__ hsb,
                              const float* __restrict__ b, float* __restrict__ out, int n) {
    __shared__ unsigned sred[256];
    int t = threadIdx.x;
    int node0 = blockIdx.x * 4;
    int c0 = node0 >> 8;
    unsigned partial = 0;
    for (int i = t; i < c0; i += 256) partial += bsum[i];
    sred[t] = partial;
    __syncthreads();
    #pragma unroll
    for (int d = 128; d > 0; d >>= 1) {
        if (t < d) sred[t] += sred[t + d];
        __syncthreads();
    }
    unsigned pref = sred[0];

    int node = node0 + (t >> 6);
    if (node >= n) return;          // wave-uniform (64 lanes = one node)
    int lane = t & 63;
    int g = lane >> 3;          // edge group 0..7
    int l = lane & 7;           // uint4 slot within 128B row (channels 8l..8l+7)
    unsigned off = offs[node] + pref;
    unsigned dg  = deg[node];
    float a0 = 0.f, a1 = 0.f, a2 = 0.f, a3 = 0.f, a4 = 0.f, a5 = 0.f, a6 = 0.f, a7 = 0.f;
    unsigned k = 0;
    for (; k + 16 <= dg; k += 16) {
        unsigned s0 = ssrc[off + k + g];
        unsigned s1 = ssrc[off + k + 8 + g];
        uint4 v0 = ((const uint4*)(hsb + (size_t)s0 * C))[l];
        uint4 v1 = ((const uint4*)(hsb + (size_t)s1 * C))[l];
        a0 += bflo(v0.x) + bflo(v1.x); a1 += bfhi(v0.x) + bfhi(v1.x);
        a2 += bflo(v0.y) + bflo(v1.y); a3 += bfhi(v0.y) + bfhi(v1.y);
        a4 += bflo(v0.z) + bflo(v1.z); a5 += bfhi(v0.z) + bfhi(v1.z);
        a6 += bflo(v0.w) + bflo(v1.w); a7 += bfhi(v0.w) + bfhi(v1.w);
    }
    if (k + 8 <= dg) {
        unsigned s0 = ssrc[off + k + g];
        uint4 v0 = ((const uint4*)(hsb + (size_t)s0 * C))[l];
        a0 += bflo(v0.x); a1 += bfhi(v0.x);
        a2 += bflo(v0.y); a3 += bfhi(v0.y);
        a4 += bflo(v0.z); a5 += bfhi(v0.z);
        a6 += bflo(v0.w); a7 += bfhi(v0.w);
        k += 8;
    }
    if (k + g < dg) {
        unsigned s0 = ssrc[off + k + g];
        uint4 v0 = ((const uint4*)(hsb + (size_t)s0 * C))[l];
        a0 += bflo(v0.x); a1 += bfhi(v0.x);
        a2 += bflo(v0.y); a3 += bfhi(v0.y);
        a4 += bflo(v0.z); a5 += bfhi(v0.z);
        a6 += bflo(v0.w); a7 += bfhi(v0.w);
    }
    // reduce across the 8 edge groups (xor 8, 16, 32)
    #pragma unroll
    for (int m = 8; m <= 32; m <<= 1) {
        a0 += __shfl_xor(a0, m); a1 += __shfl_xor(a1, m);
        a2 += __shfl_xor(a2, m); a3 += __shfl_xor(a3, m);
        a4 += __shfl_xor(a4, m); a5 += __shfl_xor(a5, m);
        a6 += __shfl_xor(a6, m); a7 += __shfl_xor(a7, m);
    }
    // groups 0/1 write the two float4 halves of the row
    if (g < 2) {
        float di = dis[node];
        uint4 u = ((const uint4*)(hsb + (size_t)node * C))[l];
        unsigned w0 = (g == 0) ? u.x : u.z;
        unsigned w1 = (g == 0) ? u.y : u.w;
        float s0 = bflo(w0), s1 = bfhi(w0), s2 = bflo(w1), s3 = bfhi(w1);
        float e0 = (g == 0) ? a0 : a4;
        float e1 = (g == 0) ? a1 : a5;
        float e2 = (g == 0) ? a2 : a6;
        float e3 = (g == 0) ? a3 : a7;
        float4 bv = ((const float4*)b)[l * 2 + g];
        float4 o;
        o.x = di * (s0 + e0) + bv.x;
        o.y = di * (s1 + e1) + bv.y;
        o.z = di * (s2 + e2) + bv.z;
        o.w = di * (s3 + e3) + bv.w;
        ((float4*)(out + (size_t)node * C))[l * 2 + g] = o;
    }
}

extern "C" void kernel_launch(void* const* d_in, const int* in_sizes, int n_in,
                              void* d_out, int out_size, void* d_ws, size_t ws_size,
                              hipStream_t stream) {
    const float* x   = (const float*)d_in[0];
    const int*   ei  = (const int*)d_in[1];   // [2, E]: src = ei[e], dst = ei[E+e]
    const float* W   = (const float*)d_in[2];
    const float* b   = (const float*)d_in[3];
    float*       out = (float*)d_out;

    const int N = in_sizes[0] / C;
    const int E = in_sizes[1] / 2;
    const int* src = ei;
    const int* dst = ei + E;

    const int S = (N + 63) & ~63;    // per-XCD partial stride
    const int nch = (N + 255) >> 8;  // chunks of 256 nodes (<= 512 for the LDS scan)

    // workspace layout (256B aligned slots)
    char* ws = (char*)d_ws;
    size_t o = 0;
    auto carve = [&](size_t bytes) { char* p = ws + o; o = (o + bytes + 255) & ~(size_t)255; return p; };
    unsigned* part      = (unsigned*)carve((size_t)8 * S * 4);
    unsigned* deg       = (unsigned*)carve((size_t)N * 4);
    unsigned* offs      = (unsigned*)carve((size_t)N * 4);
    unsigned* bsum      = (unsigned*)carve(1024 * 4);
    float*    dis       = (float*)carve((size_t)N * 4);
    unsigned* rank      = (unsigned*)carve((size_t)E * 4);
    unsigned* ssrc      = (unsigned*)carve((size_t)E * 4);
    unsigned short* hsb = (unsigned short*)carve((size_t)N * C * 2);

    // K1: zero the partial histograms (8*S u32 = 2*S uint4)
    int n4 = 2 * S;
    zero_kernel<<<(n4 + 255) / 256, 256, 0, stream>>>((uint4*)part, n4);

    // K2: per-XCD histogram + packed (xcd, local-rank), 4 edges/thread
    int ng = (E + 3) / 4;
    count_part_kernel<<<(ng + 255) / 256, 256, 0, stream>>>(dst, part, S, rank, E);

    // K3: fused chunk-scan + gemm
    scan_gemm_kernel<<<nch, 256, 0, stream>>>(part, S, x, W, deg, offs, bsum, dis, hsb, N);

    // K4: bucket (replicated bsum scan in-block)
    bucket_kernel<<<(ng + 255) / 256, 256, 0, stream>>>(src, dst, offs, bsum, part, S, rank, ssrc, E, nch);

    // K5: gather + self loop + bias
    gather_kernel<<<(N + 3) / 4, 256, 0, stream>>>(offs, bsum, deg, ssrc, dis, hsb, b, out, N);
}

// Round 14
// 139.163 us; speedup vs baseline: 3.6457x; 1.0646x over previous
//
#include <hip/hip_runtime.h>
#include <hip/hip_bf16.h>

#define C 64

// bf16 helpers (manual RNE pack / cheap unpack)
__device__ __forceinline__ float bflo(unsigned u) { return __uint_as_float(u << 16); }
__device__ __forceinline__ float bfhi(unsigned u) { return __uint_as_float(u & 0xffff0000u); }
__device__ __forceinline__ unsigned bfrne(float f) {
    unsigned u = __float_as_uint(f);
    return (u + 0x7fffu + ((u >> 16) & 1u)) >> 16;
}

// hwreg(HW_REG_XCC_ID=20, offset=0, width=4) -> simm16 = 20 | (4-1)<<11 = 6164
__device__ __forceinline__ unsigned xcc_id() {
    return __builtin_amdgcn_s_getreg(6164) & 7u;
}

// ---- K1: zero the 8 per-XCD partial histograms + global chunk counter ----
__global__ void zero_kernel(uint4* __restrict__ p, int n4, unsigned* __restrict__ gctr) {
    int i = blockIdx.x * blockDim.x + threadIdx.x;
    if (i < n4) p[i] = make_uint4(0u, 0u, 0u, 0u);
    if (i == 0) *gctr = 0u;
}

// ---- K2: per-XCD degree histogram; 4 edges/thread (uint4 dst load, uint4 rank store) ----
// Workgroup-scope atomic -> no sc1 -> RMW stays in the issuing XCD's L2.
__global__ void count_part_kernel(const int* __restrict__ dst, unsigned* __restrict__ part,
                                  int S, unsigned* __restrict__ rank, int E) {
    int g = blockIdx.x * blockDim.x + threadIdx.x;
    int e0 = g * 4;
    if (e0 >= E) return;
    unsigned x = xcc_id();
    unsigned xbase = x * (unsigned)S;
    if (e0 + 4 <= E) {
        uint4 d4 = ((const uint4*)dst)[g];
        uint4 r4;
        r4.x = (x << 27) | __hip_atomic_fetch_add(&part[xbase + d4.x], 1u, __ATOMIC_RELAXED, __HIP_MEMORY_SCOPE_WORKGROUP);
        r4.y = (x << 27) | __hip_atomic_fetch_add(&part[xbase + d4.y], 1u, __ATOMIC_RELAXED, __HIP_MEMORY_SCOPE_WORKGROUP);
        r4.z = (x << 27) | __hip_atomic_fetch_add(&part[xbase + d4.z], 1u, __ATOMIC_RELAXED, __HIP_MEMORY_SCOPE_WORKGROUP);
        r4.w = (x << 27) | __hip_atomic_fetch_add(&part[xbase + d4.w], 1u, __ATOMIC_RELAXED, __HIP_MEMORY_SCOPE_WORKGROUP);
        ((uint4*)rank)[g] = r4;
    } else {
        for (int e = e0; e < E; ++e) {
            unsigned d = (unsigned)dst[e];
            unsigned r = __hip_atomic_fetch_add(&part[xbase + d], 1u, __ATOMIC_RELAXED, __HIP_MEMORY_SCOPE_WORKGROUP);
            rank[e] = (x << 27) | r;
        }
    }
}

// ---- K3: fused per-chunk scan + gemm (chunk = 256 nodes, 4 tiles of 64 rows) ----
// Phase A: deg = sum of 8 partials (part <- cross-xcd exclusive prefix);
//          dis = rsqrt(deg+1); GLOBAL offs via one atomicAdd(gctr, chunk_sum)
//          per block (arrival-ordered chunk bases: layout permutes, sums don't).
// Phase B: hs(bf16) = dis * (x @ W) for the same 256 rows; W staged once/block.
__global__ void __launch_bounds__(256, 4)
scan_gemm_kernel(unsigned* __restrict__ part, int S,
                 const float* __restrict__ x, const float* __restrict__ W,
                 unsigned* __restrict__ deg, unsigned* __restrict__ offs,
                 unsigned* __restrict__ gctr, float* __restrict__ dis,
                 unsigned short* __restrict__ hsb, int N) {
    __shared__ float Wl[64][64];
    __shared__ float Xl[64][68];
    __shared__ unsigned s[256];
    __shared__ float sdis[256];
    __shared__ unsigned sbase;
    int t = threadIdx.x;
    int nbase = blockIdx.x * 256;

    // stage W (once per block)
    for (int i = t; i < 1024; i += 256) {
        ((float4*)Wl)[i] = ((const float4*)W)[i];
    }

    // --- phase A: one node per thread ---
    int i = nbase + t;
    unsigned degv = 0;
    if (i < N) {
        unsigned run = 0;
        #pragma unroll
        for (int xx = 0; xx < 8; ++xx) {
            unsigned* p = &part[(size_t)xx * S + i];
            unsigned v = *p;
            *p = run;                 // exclusive prefix across xcds
            run += v;
        }
        degv = run;
        deg[i] = run;
        float dv = rsqrtf((float)(run + 1u));
        dis[i] = dv;
        sdis[t] = dv;
    } else {
        sdis[t] = 0.f;
    }
    s[t] = degv;
    __syncthreads();
    for (int d = 1; d < 256; d <<= 1) {
        unsigned v = (t >= d) ? s[t - d] : 0u;
        __syncthreads();
        s[t] += v;
        __syncthreads();
    }
    if (t == 255) sbase = atomicAdd(gctr, s[255]);   // global chunk base
    __syncthreads();
    if (i < N) offs[i] = sbase + s[t] - degv;        // global exclusive offset
    __syncthreads();

    // --- phase B: 4 gemm tiles of 64 rows ---
    int tx = t & 15;      // channel group
    int ty = t >> 4;      // row group
    for (int tile = 0; tile < 4; ++tile) {
        int rbase = nbase + tile * 64;
        if (rbase >= N) break;            // block-uniform
        for (int ii = t; ii < 1024; ii += 256) {
            int r = ii >> 4, kq = ii & 15;
            float4 v;
            if (rbase + r < N) v = ((const float4*)(x + (size_t)(rbase + r) * C))[kq];
            else               v = make_float4(0.f, 0.f, 0.f, 0.f);
            *(float4*)&Xl[r][kq * 4] = v;
        }
        __syncthreads();
        float4 acc[4];
        #pragma unroll
        for (int j = 0; j < 4; ++j) acc[j] = make_float4(0.f, 0.f, 0.f, 0.f);
        #pragma unroll 2
        for (int kb = 0; kb < 16; ++kb) {
            float4 wv0 = *(const float4*)&Wl[kb * 4 + 0][tx * 4];
            float4 wv1 = *(const float4*)&Wl[kb * 4 + 1][tx * 4];
            float4 wv2 = *(const float4*)&Wl[kb * 4 + 2][tx * 4];
            float4 wv3 = *(const float4*)&Wl[kb * 4 + 3][tx * 4];
            #pragma unroll
            for (int j = 0; j < 4; ++j) {
                float4 xv = *(const float4*)&Xl[ty * 4 + j][kb * 4];
                acc[j].x = fmaf(xv.x, wv0.x, acc[j].x);
                acc[j].y = fmaf(xv.x, wv0.y, acc[j].y);
                acc[j].z = fmaf(xv.x, wv0.z, acc[j].z);
                acc[j].w = fmaf(xv.x, wv0.w, acc[j].w);
                acc[j].x = fmaf(xv.y, wv1.x, acc[j].x);
                acc[j].y = fmaf(xv.y, wv1.y, acc[j].y);
                acc[j].z = fmaf(xv.y, wv1.z, acc[j].z);
                acc[j].w = fmaf(xv.y, wv1.w, acc[j].w);
                acc[j].x = fmaf(xv.z, wv2.x, acc[j].x);
                acc[j].y = fmaf(xv.z, wv2.y, acc[j].y);
                acc[j].z = fmaf(xv.z, wv2.z, acc[j].z);
                acc[j].w = fmaf(xv.z, wv2.w, acc[j].w);
                acc[j].x = fmaf(xv.w, wv3.x, acc[j].x);
                acc[j].y = fmaf(xv.w, wv3.y, acc[j].y);
                acc[j].z = fmaf(xv.w, wv3.z, acc[j].z);
                acc[j].w = fmaf(xv.w, wv3.w, acc[j].w);
            }
        }
        #pragma unroll
        for (int j = 0; j < 4; ++j) {
            int row = rbase + ty * 4 + j;
            if (row < N) {
                float d = sdis[tile * 64 + ty * 4 + j];
                unsigned p0 = bfrne(acc[j].x * d) | (bfrne(acc[j].y * d) << 16);
                unsigned p1 = bfrne(acc[j].z * d) | (bfrne(acc[j].w * d) << 16);
                ((uint2*)(hsb + (size_t)row * C))[tx] = make_uint2(p0, p1);
            }
        }
        __syncthreads();   // before next tile overwrites Xl
    }
}

// ---- K4: bucket edges by dst (global offs; atomic-free) ----
__global__ void __launch_bounds__(256)
bucket_kernel(const int* __restrict__ src, const int* __restrict__ dst,
              const unsigned* __restrict__ offs,
              const unsigned* __restrict__ part, int S,
              const unsigned* __restrict__ rank, unsigned* __restrict__ ssrc, int E) {
    int g = blockIdx.x * 256 + threadIdx.x;
    int e0 = g * 4;
    if (e0 >= E) return;
    if (e0 + 4 <= E) {
        uint4 d4 = ((const uint4*)dst)[g];
        uint4 s4 = ((const uint4*)src)[g];
        uint4 r4 = ((const uint4*)rank)[g];
        #define PLACE(dd, ss, uu) { \
            unsigned xx = (uu) >> 27; \
            unsigned pos = offs[dd] + part[(size_t)xx * S + (dd)] + ((uu) & 0x07FFFFFFu); \
            ssrc[pos] = (ss); }
        PLACE(d4.x, s4.x, r4.x);
        PLACE(d4.y, s4.y, r4.y);
        PLACE(d4.z, s4.z, r4.z);
        PLACE(d4.w, s4.w, r4.w);
        #undef PLACE
    } else {
        for (int e = e0; e < E; ++e) {
            unsigned dd = (unsigned)dst[e];
            unsigned uu = rank[e];
            unsigned xx = uu >> 27;
            unsigned pos = offs[dd] + part[(size_t)xx * S + dd] + (uu & 0x07FFFFFFu);
            ssrc[pos] = (unsigned)src[e];
        }
    }
}

// ---- K5: gather; one wave/node; first 16 edge indices in ONE coalesced round ----
// Mean deg=10: old code did serial {ssrc load -> row load} per 8-edge round
// (~4 dependent latencies). Now lanes 0..15 fetch 16 indices at once; groups
// get theirs via shfl, so both 8-edge row rounds issue back-to-back (~2).
__global__ void gather_kernel(const unsigned* __restrict__ offs,
                              const unsigned* __restrict__ deg, const unsigned* __restrict__ ssrc,
                              const float* __restrict__ dis, const unsigned short* __restrict__ hsb,
                              const float* __restrict__ b, float* __restrict__ out, int n) {
    int node = blockIdx.x * 4 + (threadIdx.x >> 6);
    if (node >= n) return;
    int lane = threadIdx.x & 63;
    int g = lane >> 3;          // edge group 0..7
    int l = lane & 7;           // uint4 slot within 128B row (channels 8l..8l+7)
    unsigned off = offs[node];
    unsigned dg  = deg[node];
    float a0 = 0.f, a1 = 0.f, a2 = 0.f, a3 = 0.f, a4 = 0.f, a5 = 0.f, a6 = 0.f, a7 = 0.f;
    if (dg) {
        // one coalesced round for the first 16 indices
        unsigned l15 = (unsigned)lane & 15u;
        unsigned cl  = (l15 < dg) ? l15 : dg - 1u;
        unsigned idxv = ssrc[off + cl];
        #pragma unroll
        for (int r = 0; r < 2; ++r) {
            unsigned k = (unsigned)(r * 8) + (unsigned)g;
            unsigned sK = (unsigned)__shfl((int)idxv, (int)k);
            if (k < dg) {
                uint4 v0 = ((const uint4*)(hsb + (size_t)sK * C))[l];
                a0 += bflo(v0.x); a1 += bfhi(v0.x);
                a2 += bflo(v0.y); a3 += bfhi(v0.y);
                a4 += bflo(v0.z); a5 += bfhi(v0.z);
                a6 += bflo(v0.w); a7 += bfhi(v0.w);
            }
        }
        // rare heavy nodes (deg > 16)
        unsigned k = 16;
        for (; k + 8 <= dg; k += 8) {
            unsigned s0 = ssrc[off + k + g];
            uint4 v0 = ((const uint4*)(hsb + (size_t)s0 * C))[l];
            a0 += bflo(v0.x); a1 += bfhi(v0.x);
            a2 += bflo(v0.y); a3 += bfhi(v0.y);
            a4 += bflo(v0.z); a5 += bfhi(v0.z);
            a6 += bflo(v0.w); a7 += bfhi(v0.w);
        }
        if (k + g < dg && k > 16u - 8u + 16u - 16u) { /* keep structure simple */ }
        if (k + g < dg) {
            unsigned s0 = ssrc[off + k + g];
            uint4 v0 = ((const uint4*)(hsb + (size_t)s0 * C))[l];
            a0 += bflo(v0.x); a1 += bfhi(v0.x);
            a2 += bflo(v0.y); a3 += bfhi(v0.y);
            a4 += bflo(v0.z); a5 += bfhi(v0.z);
            a6 += bflo(v0.w); a7 += bfhi(v0.w);
        }
    }
    // reduce across the 8 edge groups (xor 8, 16, 32)
    #pragma unroll
    for (int m = 8; m <= 32; m <<= 1) {
        a0 += __shfl_xor(a0, m); a1 += __shfl_xor(a1, m);
        a2 += __shfl_xor(a2, m); a3 += __shfl_xor(a3, m);
        a4 += __shfl_xor(a4, m); a5 += __shfl_xor(a5, m);
        a6 += __shfl_xor(a6, m); a7 += __shfl_xor(a7, m);
    }
    // groups 0/1 write the two float4 halves of the row
    if (g < 2) {
        float di = dis[node];
        uint4 u = ((const uint4*)(hsb + (size_t)node * C))[l];
        unsigned w0 = (g == 0) ? u.x : u.z;
        unsigned w1 = (g == 0) ? u.y : u.w;
        float s0 = bflo(w0), s1 = bfhi(w0), s2 = bflo(w1), s3 = bfhi(w1);
        float e0 = (g == 0) ? a0 : a4;
        float e1 = (g == 0) ? a1 : a5;
        float e2 = (g == 0) ? a2 : a6;
        float e3 = (g == 0) ? a3 : a7;
        float4 bv = ((const float4*)b)[l * 2 + g];
        float4 o;
        o.x = di * (s0 + e0) + bv.x;
        o.y = di * (s1 + e1) + bv.y;
        o.z = di * (s2 + e2) + bv.z;
        o.w = di * (s3 + e3) + bv.w;
        ((float4*)(out + (size_t)node * C))[l * 2 + g] = o;
    }
}

extern "C" void kernel_launch(void* const* d_in, const int* in_sizes, int n_in,
                              void* d_out, int out_size, void* d_ws, size_t ws_size,
                              hipStream_t stream) {
    const float* x   = (const float*)d_in[0];
    const int*   ei  = (const int*)d_in[1];   // [2, E]: src = ei[e], dst = ei[E+e]
    const float* W   = (const float*)d_in[2];
    const float* b   = (const float*)d_in[3];
    float*       out = (float*)d_out;

    const int N = in_sizes[0] / C;
    const int E = in_sizes[1] / 2;
    const int* src = ei;
    const int* dst = ei + E;

    const int S   = (N + 63) & ~63;   // per-XCD partial stride
    const int nch = (N + 255) >> 8;   // chunks of 256 nodes

    // workspace layout (256B aligned slots)
    char* ws = (char*)d_ws;
    size_t o = 0;
    auto carve = [&](size_t bytes) { char* p = ws + o; o = (o + bytes + 255) & ~(size_t)255; return p; };
    unsigned* part      = (unsigned*)carve((size_t)8 * S * 4);
    unsigned* deg       = (unsigned*)carve((size_t)N * 4);
    unsigned* offs      = (unsigned*)carve((size_t)N * 4);
    unsigned* gctr      = (unsigned*)carve(256);
    float*    dis       = (float*)carve((size_t)N * 4);
    unsigned* rank      = (unsigned*)carve((size_t)E * 4);
    unsigned* ssrc      = (unsigned*)carve((size_t)E * 4);
    unsigned short* hsb = (unsigned short*)carve((size_t)N * C * 2);

    // K1: zero the partial histograms + chunk counter
    int n4 = 2 * S;
    zero_kernel<<<(n4 + 255) / 256, 256, 0, stream>>>((uint4*)part, n4, gctr);

    // K2: per-XCD histogram + packed (xcd, local-rank), 4 edges/thread
    int ng = (E + 3) / 4;
    count_part_kernel<<<(ng + 255) / 256, 256, 0, stream>>>(dst, part, S, rank, E);

    // K3: fused chunk-scan + gemm (global offs via gctr)
    scan_gemm_kernel<<<nch, 256, 0, stream>>>(part, S, x, W, deg, offs, gctr, dis, hsb, N);

    // K4: bucket
    bucket_kernel<<<(ng + 255) / 256, 256, 0, stream>>>(src, dst, offs, part, S, rank, ssrc, E);

    // K5: gather + self loop + bias
    gather_kernel<<<(N + 3) / 4, 256, 0, stream>>>(offs, deg, ssrc, dis, hsb, b, out, N);
}

// Round 15
// 132.987 us; speedup vs baseline: 3.8150x; 1.0464x over previous
//
#include <hip/hip_runtime.h>
#include <hip/hip_bf16.h>
#include <hip/hip_fp16.h>

#define C 64

// hwreg(HW_REG_XCC_ID=20, offset=0, width=4) -> simm16 = 20 | (4-1)<<11 = 6164
__device__ __forceinline__ unsigned xcc_id() {
    return __builtin_amdgcn_s_getreg(6164) & 7u;
}

__device__ __forceinline__ __half2 u2h(unsigned u) {
    __half2 h; *(unsigned*)&h = u; return h;
}
__device__ __forceinline__ unsigned h2u(__half2 h) {
    return *(unsigned*)&h;
}

// ---- K1: zero the 8 per-XCD partial histograms + global chunk counter ----
__global__ void zero_kernel(uint4* __restrict__ p, int n4, unsigned* __restrict__ gctr) {
    int i = blockIdx.x * blockDim.x + threadIdx.x;
    if (i < n4) p[i] = make_uint4(0u, 0u, 0u, 0u);
    if (i == 0) *gctr = 0u;
}

// ---- K2: per-XCD degree histogram; 4 edges/thread ----
// Workgroup-scope atomic -> no sc1 -> RMW stays in the issuing XCD's L2.
__global__ void count_part_kernel(const int* __restrict__ dst, unsigned* __restrict__ part,
                                  int S, unsigned* __restrict__ rank, int E) {
    int g = blockIdx.x * blockDim.x + threadIdx.x;
    int e0 = g * 4;
    if (e0 >= E) return;
    unsigned x = xcc_id();
    unsigned xbase = x * (unsigned)S;
    if (e0 + 4 <= E) {
        uint4 d4 = ((const uint4*)dst)[g];
        uint4 r4;
        r4.x = (x << 27) | __hip_atomic_fetch_add(&part[xbase + d4.x], 1u, __ATOMIC_RELAXED, __HIP_MEMORY_SCOPE_WORKGROUP);
        r4.y = (x << 27) | __hip_atomic_fetch_add(&part[xbase + d4.y], 1u, __ATOMIC_RELAXED, __HIP_MEMORY_SCOPE_WORKGROUP);
        r4.z = (x << 27) | __hip_atomic_fetch_add(&part[xbase + d4.z], 1u, __ATOMIC_RELAXED, __HIP_MEMORY_SCOPE_WORKGROUP);
        r4.w = (x << 27) | __hip_atomic_fetch_add(&part[xbase + d4.w], 1u, __ATOMIC_RELAXED, __HIP_MEMORY_SCOPE_WORKGROUP);
        ((uint4*)rank)[g] = r4;
    } else {
        for (int e = e0; e < E; ++e) {
            unsigned d = (unsigned)dst[e];
            unsigned r = __hip_atomic_fetch_add(&part[xbase + d], 1u, __ATOMIC_RELAXED, __HIP_MEMORY_SCOPE_WORKGROUP);
            rank[e] = (x << 27) | r;
        }
    }
}

// ---- K3: fused per-chunk scan + gemm (chunk = 256 nodes, 4 tiles of 64 rows) ----
// hs stored as fp16 now (10-bit mantissa > bf16's 7; enables pk_add in gather).
__global__ void __launch_bounds__(256, 4)
scan_gemm_kernel(unsigned* __restrict__ part, int S,
                 const float* __restrict__ x, const float* __restrict__ W,
                 unsigned* __restrict__ deg, unsigned* __restrict__ offs,
                 unsigned* __restrict__ gctr, float* __restrict__ dis,
                 unsigned short* __restrict__ hsb, int N) {
    __shared__ float Wl[64][64];
    __shared__ float Xl[64][68];
    __shared__ unsigned s[256];
    __shared__ float sdis[256];
    __shared__ unsigned sbase;
    int t = threadIdx.x;
    int nbase = blockIdx.x * 256;

    for (int i = t; i < 1024; i += 256) {
        ((float4*)Wl)[i] = ((const float4*)W)[i];
    }

    // --- phase A: one node per thread ---
    int i = nbase + t;
    unsigned degv = 0;
    if (i < N) {
        unsigned run = 0;
        #pragma unroll
        for (int xx = 0; xx < 8; ++xx) {
            unsigned* p = &part[(size_t)xx * S + i];
            unsigned v = *p;
            *p = run;                 // exclusive prefix across xcds
            run += v;
        }
        degv = run;
        deg[i] = run;
        float dv = rsqrtf((float)(run + 1u));
        dis[i] = dv;
        sdis[t] = dv;
    } else {
        sdis[t] = 0.f;
    }
    s[t] = degv;
    __syncthreads();
    for (int d = 1; d < 256; d <<= 1) {
        unsigned v = (t >= d) ? s[t - d] : 0u;
        __syncthreads();
        s[t] += v;
        __syncthreads();
    }
    if (t == 255) sbase = atomicAdd(gctr, s[255]);   // global chunk base
    __syncthreads();
    if (i < N) offs[i] = sbase + s[t] - degv;        // global exclusive offset
    __syncthreads();

    // --- phase B: 4 gemm tiles of 64 rows ---
    int tx = t & 15;      // channel group
    int ty = t >> 4;      // row group
    for (int tile = 0; tile < 4; ++tile) {
        int rbase = nbase + tile * 64;
        if (rbase >= N) break;            // block-uniform
        for (int ii = t; ii < 1024; ii += 256) {
            int r = ii >> 4, kq = ii & 15;
            float4 v;
            if (rbase + r < N) v = ((const float4*)(x + (size_t)(rbase + r) * C))[kq];
            else               v = make_float4(0.f, 0.f, 0.f, 0.f);
            *(float4*)&Xl[r][kq * 4] = v;
        }
        __syncthreads();
        float4 acc[4];
        #pragma unroll
        for (int j = 0; j < 4; ++j) acc[j] = make_float4(0.f, 0.f, 0.f, 0.f);
        #pragma unroll 2
        for (int kb = 0; kb < 16; ++kb) {
            float4 wv0 = *(const float4*)&Wl[kb * 4 + 0][tx * 4];
            float4 wv1 = *(const float4*)&Wl[kb * 4 + 1][tx * 4];
            float4 wv2 = *(const float4*)&Wl[kb * 4 + 2][tx * 4];
            float4 wv3 = *(const float4*)&Wl[kb * 4 + 3][tx * 4];
            #pragma unroll
            for (int j = 0; j < 4; ++j) {
                float4 xv = *(const float4*)&Xl[ty * 4 + j][kb * 4];
                acc[j].x = fmaf(xv.x, wv0.x, acc[j].x);
                acc[j].y = fmaf(xv.x, wv0.y, acc[j].y);
                acc[j].z = fmaf(xv.x, wv0.z, acc[j].z);
                acc[j].w = fmaf(xv.x, wv0.w, acc[j].w);
                acc[j].x = fmaf(xv.y, wv1.x, acc[j].x);
                acc[j].y = fmaf(xv.y, wv1.y, acc[j].y);
                acc[j].z = fmaf(xv.y, wv1.z, acc[j].z);
                acc[j].w = fmaf(xv.y, wv1.w, acc[j].w);
                acc[j].x = fmaf(xv.z, wv2.x, acc[j].x);
                acc[j].y = fmaf(xv.z, wv2.y, acc[j].y);
                acc[j].z = fmaf(xv.z, wv2.z, acc[j].z);
                acc[j].w = fmaf(xv.z, wv2.w, acc[j].w);
                acc[j].x = fmaf(xv.w, wv3.x, acc[j].x);
                acc[j].y = fmaf(xv.w, wv3.y, acc[j].y);
                acc[j].z = fmaf(xv.w, wv3.z, acc[j].z);
                acc[j].w = fmaf(xv.w, wv3.w, acc[j].w);
            }
        }
        #pragma unroll
        for (int j = 0; j < 4; ++j) {
            int row = rbase + ty * 4 + j;
            if (row < N) {
                float d = sdis[tile * 64 + ty * 4 + j];
                __half2 h0 = __floats2half2_rn(acc[j].x * d, acc[j].y * d);
                __half2 h1 = __floats2half2_rn(acc[j].z * d, acc[j].w * d);
                ((uint2*)(hsb + (size_t)row * C))[tx] = make_uint2(h2u(h0), h2u(h1));
            }
        }
        __syncthreads();   // before next tile overwrites Xl
    }
}

// ---- K4: bucket edges by dst (global offs; atomic-free) ----
__global__ void __launch_bounds__(256)
bucket_kernel(const int* __restrict__ src, const int* __restrict__ dst,
              const unsigned* __restrict__ offs,
              const unsigned* __restrict__ part, int S,
              const unsigned* __restrict__ rank, unsigned* __restrict__ ssrc, int E) {
    int g = blockIdx.x * 256 + threadIdx.x;
    int e0 = g * 4;
    if (e0 >= E) return;
    if (e0 + 4 <= E) {
        uint4 d4 = ((const uint4*)dst)[g];
        uint4 s4 = ((const uint4*)src)[g];
        uint4 r4 = ((const uint4*)rank)[g];
        #define PLACE(dd, ss, uu) { \
            unsigned xx = (uu) >> 27; \
            unsigned pos = offs[dd] + part[(size_t)xx * S + (dd)] + ((uu) & 0x07FFFFFFu); \
            ssrc[pos] = (ss); }
        PLACE(d4.x, s4.x, r4.x);
        PLACE(d4.y, s4.y, r4.y);
        PLACE(d4.z, s4.z, r4.z);
        PLACE(d4.w, s4.w, r4.w);
        #undef PLACE
    } else {
        for (int e = e0; e < E; ++e) {
            unsigned dd = (unsigned)dst[e];
            unsigned uu = rank[e];
            unsigned xx = uu >> 27;
            unsigned pos = offs[dd] + part[(size_t)xx * S + dd] + (uu & 0x07FFFFFFu);
            ssrc[pos] = (unsigned)src[e];
        }
    }
}

// ---- K5: gather; one wave/node; fp16 rows, packed-half2 accumulation ----
// Per uint4 (8 fp16): 4 v_pk_add_f16 vs bf16's 16 VALU ops (R14: VALUBusy 42%).
// Group-reduce shuffles 4 ints instead of 8 floats.
__global__ void gather_kernel(const unsigned* __restrict__ offs,
                              const unsigned* __restrict__ deg, const unsigned* __restrict__ ssrc,
                              const float* __restrict__ dis, const unsigned short* __restrict__ hsb,
                              const float* __restrict__ b, float* __restrict__ out, int n) {
    int node = blockIdx.x * 4 + (threadIdx.x >> 6);
    if (node >= n) return;
    int lane = threadIdx.x & 63;
    int g = lane >> 3;          // edge group 0..7
    int l = lane & 7;           // uint4 slot within 128B row (channels 8l..8l+7)
    unsigned off = offs[node];
    unsigned dg  = deg[node];
    __half2 a0 = u2h(0u), a1 = u2h(0u), a2 = u2h(0u), a3 = u2h(0u);
    if (dg) {
        // one coalesced round for the first 16 indices; groups pull via shfl
        unsigned l15 = (unsigned)lane & 15u;
        unsigned cl  = (l15 < dg) ? l15 : dg - 1u;
        unsigned idxv = ssrc[off + cl];
        #pragma unroll
        for (int r = 0; r < 2; ++r) {
            unsigned k = (unsigned)(r * 8) + (unsigned)g;
            unsigned sK = (unsigned)__shfl((int)idxv, (int)k);
            if (k < dg) {
                uint4 v = ((const uint4*)(hsb + (size_t)sK * C))[l];
                a0 = __hadd2(a0, u2h(v.x));
                a1 = __hadd2(a1, u2h(v.y));
                a2 = __hadd2(a2, u2h(v.z));
                a3 = __hadd2(a3, u2h(v.w));
            }
        }
        // rare heavy nodes (deg > 16)
        unsigned k = 16;
        for (; k + 8 <= dg; k += 8) {
            unsigned s0 = ssrc[off + k + g];
            uint4 v = ((const uint4*)(hsb + (size_t)s0 * C))[l];
            a0 = __hadd2(a0, u2h(v.x));
            a1 = __hadd2(a1, u2h(v.y));
            a2 = __hadd2(a2, u2h(v.z));
            a3 = __hadd2(a3, u2h(v.w));
        }
        if (k + g < dg) {
            unsigned s0 = ssrc[off + k + g];
            uint4 v = ((const uint4*)(hsb + (size_t)s0 * C))[l];
            a0 = __hadd2(a0, u2h(v.x));
            a1 = __hadd2(a1, u2h(v.y));
            a2 = __hadd2(a2, u2h(v.z));
            a3 = __hadd2(a3, u2h(v.w));
        }
    }
    // reduce across the 8 edge groups (xor 8, 16, 32) in packed fp16
    #pragma unroll
    for (int m = 8; m <= 32; m <<= 1) {
        a0 = __hadd2(a0, u2h((unsigned)__shfl_xor((int)h2u(a0), m)));
        a1 = __hadd2(a1, u2h((unsigned)__shfl_xor((int)h2u(a1), m)));
        a2 = __hadd2(a2, u2h((unsigned)__shfl_xor((int)h2u(a2), m)));
        a3 = __hadd2(a3, u2h((unsigned)__shfl_xor((int)h2u(a3), m)));
    }
    // groups 0/1 write the two float4 halves of the row
    if (g < 2) {
        float di = dis[node];
        uint4 u = ((const uint4*)(hsb + (size_t)node * C))[l];
        unsigned w0 = (g == 0) ? u.x : u.z;
        unsigned w1 = (g == 0) ? u.y : u.w;
        float s0 = __low2float(u2h(w0)), s1 = __high2float(u2h(w0));
        float s2 = __low2float(u2h(w1)), s3 = __high2float(u2h(w1));
        __half2 ea = (g == 0) ? a0 : a2;
        __half2 eb = (g == 0) ? a1 : a3;
        float e0 = __low2float(ea), e1 = __high2float(ea);
        float e2 = __low2float(eb), e3 = __high2float(eb);
        float4 bv = ((const float4*)b)[l * 2 + g];
        float4 o;
        o.x = di * (s0 + e0) + bv.x;
        o.y = di * (s1 + e1) + bv.y;
        o.z = di * (s2 + e2) + bv.z;
        o.w = di * (s3 + e3) + bv.w;
        ((float4*)(out + (size_t)node * C))[l * 2 + g] = o;
    }
}

extern "C" void kernel_launch(void* const* d_in, const int* in_sizes, int n_in,
                              void* d_out, int out_size, void* d_ws, size_t ws_size,
                              hipStream_t stream) {
    const float* x   = (const float*)d_in[0];
    const int*   ei  = (const int*)d_in[1];   // [2, E]: src = ei[e], dst = ei[E+e]
    const float* W   = (const float*)d_in[2];
    const float* b   = (const float*)d_in[3];
    float*       out = (float*)d_out;

    const int N = in_sizes[0] / C;
    const int E = in_sizes[1] / 2;
    const int* src = ei;
    const int* dst = ei + E;

    const int S   = (N + 63) & ~63;   // per-XCD partial stride
    const int nch = (N + 255) >> 8;   // chunks of 256 nodes

    // workspace layout (256B aligned slots)
    char* ws = (char*)d_ws;
    size_t o = 0;
    auto carve = [&](size_t bytes) { char* p = ws + o; o = (o + bytes + 255) & ~(size_t)255; return p; };
    unsigned* part      = (unsigned*)carve((size_t)8 * S * 4);
    unsigned* deg       = (unsigned*)carve((size_t)N * 4);
    unsigned* offs      = (unsigned*)carve((size_t)N * 4);
    unsigned* gctr      = (unsigned*)carve(256);
    float*    dis       = (float*)carve((size_t)N * 4);
    unsigned* rank      = (unsigned*)carve((size_t)E * 4);
    unsigned* ssrc      = (unsigned*)carve((size_t)E * 4);
    unsigned short* hsb = (unsigned short*)carve((size_t)N * C * 2);

    // K1: zero the partial histograms + chunk counter
    int n4 = 2 * S;
    zero_kernel<<<(n4 + 255) / 256, 256, 0, stream>>>((uint4*)part, n4, gctr);

    // K2: per-XCD histogram + packed (xcd, local-rank), 4 edges/thread
    int ng = (E + 3) / 4;
    count_part_kernel<<<(ng + 255) / 256, 256, 0, stream>>>(dst, part, S, rank, E);

    // K3: fused chunk-scan + gemm (global offs via gctr)
    scan_gemm_kernel<<<nch, 256, 0, stream>>>(part, S, x, W, deg, offs, gctr, dis, hsb, N);

    // K4: bucket
    bucket_kernel<<<(ng + 255) / 256, 256, 0, stream>>>(src, dst, offs, part, S, rank, ssrc, E);

    // K5: gather + self loop + bias
    gather_kernel<<<(N + 3) / 4, 256, 0, stream>>>(offs, deg, ssrc, dis, hsb, b, out, N);
}

// Round 16
// 131.763 us; speedup vs baseline: 3.8504x; 1.0093x over previous
//
#include <hip/hip_runtime.h>
#include <hip/hip_bf16.h>
#include <hip/hip_fp16.h>

#define C 64

// hwreg(HW_REG_XCC_ID=20, offset=0, width=4) -> simm16 = 20 | (4-1)<<11 = 6164
__device__ __forceinline__ unsigned xcc_id() {
    return __builtin_amdgcn_s_getreg(6164) & 7u;
}

__device__ __forceinline__ __half2 u2h(unsigned u) {
    __half2 h; *(unsigned*)&h = u; return h;
}
__device__ __forceinline__ unsigned h2u(__half2 h) {
    return *(unsigned*)&h;
}

// ---- K1: zero the 8 per-XCD partial histograms + global chunk counter ----
__global__ void zero_kernel(uint4* __restrict__ p, int n4, unsigned* __restrict__ gctr) {
    int i = blockIdx.x * blockDim.x + threadIdx.x;
    if (i < n4) p[i] = make_uint4(0u, 0u, 0u, 0u);
    if (i == 0) *gctr = 0u;
}

// ---- K2: per-XCD degree histogram; 2 edges/thread ----
// R15 ran 4 edges/thread = 977 blocks = 3.8 blocks/CU -> too few waves to hide
// the ~500cy L2 atomic-return latency. 2/thread doubles grid-wide outstanding
// atomics. Workgroup-scope -> RMW stays in the issuing XCD's L2.
__global__ void count_part_kernel(const int* __restrict__ dst, unsigned* __restrict__ part,
                                  int S, unsigned* __restrict__ rank, int E) {
    int g = blockIdx.x * blockDim.x + threadIdx.x;
    int e0 = g * 2;
    if (e0 >= E) return;
    unsigned x = xcc_id();
    unsigned xbase = x * (unsigned)S;
    if (e0 + 2 <= E) {
        uint2 d2 = ((const uint2*)dst)[g];
        uint2 r2;
        r2.x = (x << 27) | __hip_atomic_fetch_add(&part[xbase + d2.x], 1u, __ATOMIC_RELAXED, __HIP_MEMORY_SCOPE_WORKGROUP);
        r2.y = (x << 27) | __hip_atomic_fetch_add(&part[xbase + d2.y], 1u, __ATOMIC_RELAXED, __HIP_MEMORY_SCOPE_WORKGROUP);
        ((uint2*)rank)[g] = r2;
    } else {
        unsigned d = (unsigned)dst[e0];
        unsigned r = __hip_atomic_fetch_add(&part[xbase + d], 1u, __ATOMIC_RELAXED, __HIP_MEMORY_SCOPE_WORKGROUP);
        rank[e0] = (x << 27) | r;
    }
}

// ---- K3: fused per-chunk scan + gemm (chunk = 256 nodes, 4 tiles of 64 rows) ----
__global__ void __launch_bounds__(256, 4)
scan_gemm_kernel(unsigned* __restrict__ part, int S,
                 const float* __restrict__ x, const float* __restrict__ W,
                 unsigned* __restrict__ deg, unsigned* __restrict__ offs,
                 unsigned* __restrict__ gctr, float* __restrict__ dis,
                 unsigned short* __restrict__ hsb, int N) {
    __shared__ float Wl[64][64];
    __shared__ float Xl[64][68];
    __shared__ unsigned s[256];
    __shared__ float sdis[256];
    __shared__ unsigned sbase;
    int t = threadIdx.x;
    int nbase = blockIdx.x * 256;

    for (int i = t; i < 1024; i += 256) {
        ((float4*)Wl)[i] = ((const float4*)W)[i];
    }

    // --- phase A: one node per thread ---
    int i = nbase + t;
    unsigned degv = 0;
    if (i < N) {
        unsigned run = 0;
        #pragma unroll
        for (int xx = 0; xx < 8; ++xx) {
            unsigned* p = &part[(size_t)xx * S + i];
            unsigned v = *p;
            *p = run;                 // exclusive prefix across xcds
            run += v;
        }
        degv = run;
        deg[i] = run;
        float dv = rsqrtf((float)(run + 1u));
        dis[i] = dv;
        sdis[t] = dv;
    } else {
        sdis[t] = 0.f;
    }
    s[t] = degv;
    __syncthreads();
    for (int d = 1; d < 256; d <<= 1) {
        unsigned v = (t >= d) ? s[t - d] : 0u;
        __syncthreads();
        s[t] += v;
        __syncthreads();
    }
    if (t == 255) sbase = atomicAdd(gctr, s[255]);   // global chunk base
    __syncthreads();
    if (i < N) offs[i] = sbase + s[t] - degv;        // global exclusive offset
    __syncthreads();

    // --- phase B: 4 gemm tiles of 64 rows ---
    int tx = t & 15;      // channel group
    int ty = t >> 4;      // row group
    for (int tile = 0; tile < 4; ++tile) {
        int rbase = nbase + tile * 64;
        if (rbase >= N) break;            // block-uniform
        for (int ii = t; ii < 1024; ii += 256) {
            int r = ii >> 4, kq = ii & 15;
            float4 v;
            if (rbase + r < N) v = ((const float4*)(x + (size_t)(rbase + r) * C))[kq];
            else               v = make_float4(0.f, 0.f, 0.f, 0.f);
            *(float4*)&Xl[r][kq * 4] = v;
        }
        __syncthreads();
        float4 acc[4];
        #pragma unroll
        for (int j = 0; j < 4; ++j) acc[j] = make_float4(0.f, 0.f, 0.f, 0.f);
        #pragma unroll 2
        for (int kb = 0; kb < 16; ++kb) {
            float4 wv0 = *(const float4*)&Wl[kb * 4 + 0][tx * 4];
            float4 wv1 = *(const float4*)&Wl[kb * 4 + 1][tx * 4];
            float4 wv2 = *(const float4*)&Wl[kb * 4 + 2][tx * 4];
            float4 wv3 = *(const float4*)&Wl[kb * 4 + 3][tx * 4];
            #pragma unroll
            for (int j = 0; j < 4; ++j) {
                float4 xv = *(const float4*)&Xl[ty * 4 + j][kb * 4];
                acc[j].x = fmaf(xv.x, wv0.x, acc[j].x);
                acc[j].y = fmaf(xv.x, wv0.y, acc[j].y);
                acc[j].z = fmaf(xv.x, wv0.z, acc[j].z);
                acc[j].w = fmaf(xv.x, wv0.w, acc[j].w);
                acc[j].x = fmaf(xv.y, wv1.x, acc[j].x);
                acc[j].y = fmaf(xv.y, wv1.y, acc[j].y);
                acc[j].z = fmaf(xv.y, wv1.z, acc[j].z);
                acc[j].w = fmaf(xv.y, wv1.w, acc[j].w);
                acc[j].x = fmaf(xv.z, wv2.x, acc[j].x);
                acc[j].y = fmaf(xv.z, wv2.y, acc[j].y);
                acc[j].z = fmaf(xv.z, wv2.z, acc[j].z);
                acc[j].w = fmaf(xv.z, wv2.w, acc[j].w);
                acc[j].x = fmaf(xv.w, wv3.x, acc[j].x);
                acc[j].y = fmaf(xv.w, wv3.y, acc[j].y);
                acc[j].z = fmaf(xv.w, wv3.z, acc[j].z);
                acc[j].w = fmaf(xv.w, wv3.w, acc[j].w);
            }
        }
        #pragma unroll
        for (int j = 0; j < 4; ++j) {
            int row = rbase + ty * 4 + j;
            if (row < N) {
                float d = sdis[tile * 64 + ty * 4 + j];
                __half2 h0 = __floats2half2_rn(acc[j].x * d, acc[j].y * d);
                __half2 h1 = __floats2half2_rn(acc[j].z * d, acc[j].w * d);
                ((uint2*)(hsb + (size_t)row * C))[tx] = make_uint2(h2u(h0), h2u(h1));
            }
        }
        __syncthreads();   // before next tile overwrites Xl
    }
}

// ---- K4: bucket edges by dst (global offs; atomic-free) ----
__global__ void __launch_bounds__(256)
bucket_kernel(const int* __restrict__ src, const int* __restrict__ dst,
              const unsigned* __restrict__ offs,
              const unsigned* __restrict__ part, int S,
              const unsigned* __restrict__ rank, unsigned* __restrict__ ssrc, int E) {
    int g = blockIdx.x * 256 + threadIdx.x;
    int e0 = g * 4;
    if (e0 >= E) return;
    if (e0 + 4 <= E) {
        uint4 d4 = ((const uint4*)dst)[g];
        uint4 s4 = ((const uint4*)src)[g];
        uint4 r4 = ((const uint4*)rank)[g];
        #define PLACE(dd, ss, uu) { \
            unsigned xx = (uu) >> 27; \
            unsigned pos = offs[dd] + part[(size_t)xx * S + (dd)] + ((uu) & 0x07FFFFFFu); \
            ssrc[pos] = (ss); }
        PLACE(d4.x, s4.x, r4.x);
        PLACE(d4.y, s4.y, r4.y);
        PLACE(d4.z, s4.z, r4.z);
        PLACE(d4.w, s4.w, r4.w);
        #undef PLACE
    } else {
        for (int e = e0; e < E; ++e) {
            unsigned dd = (unsigned)dst[e];
            unsigned uu = rank[e];
            unsigned xx = uu >> 27;
            unsigned pos = offs[dd] + part[(size_t)xx * S + dd] + (uu & 0x07FFFFFFu);
            ssrc[pos] = (unsigned)src[e];
        }
    }
}

// ---- K5: gather; one wave/node; fp16 rows, packed-half2 accumulation ----
// Own-row/bias/dis loads hoisted BEFORE the edge rounds: they were after the
// reduce (a full dependent latency per node); now they issue concurrently
// with idxv and the row loads.
__global__ void gather_kernel(const unsigned* __restrict__ offs,
                              const unsigned* __restrict__ deg, const unsigned* __restrict__ ssrc,
                              const float* __restrict__ dis, const unsigned short* __restrict__ hsb,
                              const float* __restrict__ b, float* __restrict__ out, int n) {
    int node = blockIdx.x * 4 + (threadIdx.x >> 6);
    if (node >= n) return;
    int lane = threadIdx.x & 63;
    int g = lane >> 3;          // edge group 0..7
    int l = lane & 7;           // uint4 slot within 128B row (channels 8l..8l+7)

    // hoisted independent loads (fill the memory pipe early)
    uint4 u = make_uint4(0u, 0u, 0u, 0u);
    float4 bv = make_float4(0.f, 0.f, 0.f, 0.f);
    float di = 0.f;
    if (g < 2) {
        u  = ((const uint4*)(hsb + (size_t)node * C))[l];
        bv = ((const float4*)b)[l * 2 + g];
        di = dis[node];
    }

    unsigned off = offs[node];
    unsigned dg  = deg[node];
    __half2 a0 = u2h(0u), a1 = u2h(0u), a2 = u2h(0u), a3 = u2h(0u);
    if (dg) {
        // one coalesced round for the first 16 indices; groups pull via shfl
        unsigned l15 = (unsigned)lane & 15u;
        unsigned cl  = (l15 < dg) ? l15 : dg - 1u;
        unsigned idxv = ssrc[off + cl];
        #pragma unroll
        for (int r = 0; r < 2; ++r) {
            unsigned k = (unsigned)(r * 8) + (unsigned)g;
            unsigned sK = (unsigned)__shfl((int)idxv, (int)k);
            if (k < dg) {
                uint4 v = ((const uint4*)(hsb + (size_t)sK * C))[l];
                a0 = __hadd2(a0, u2h(v.x));
                a1 = __hadd2(a1, u2h(v.y));
                a2 = __hadd2(a2, u2h(v.z));
                a3 = __hadd2(a3, u2h(v.w));
            }
        }
        // rare heavy nodes (deg > 16)
        unsigned k = 16;
        for (; k + 8 <= dg; k += 8) {
            unsigned s0 = ssrc[off + k + g];
            uint4 v = ((const uint4*)(hsb + (size_t)s0 * C))[l];
            a0 = __hadd2(a0, u2h(v.x));
            a1 = __hadd2(a1, u2h(v.y));
            a2 = __hadd2(a2, u2h(v.z));
            a3 = __hadd2(a3, u2h(v.w));
        }
        if (k + g < dg) {
            unsigned s0 = ssrc[off + k + g];
            uint4 v = ((const uint4*)(hsb + (size_t)s0 * C))[l];
            a0 = __hadd2(a0, u2h(v.x));
            a1 = __hadd2(a1, u2h(v.y));
            a2 = __hadd2(a2, u2h(v.z));
            a3 = __hadd2(a3, u2h(v.w));
        }
    }
    // reduce across the 8 edge groups (xor 8, 16, 32) in packed fp16
    #pragma unroll
    for (int m = 8; m <= 32; m <<= 1) {
        a0 = __hadd2(a0, u2h((unsigned)__shfl_xor((int)h2u(a0), m)));
        a1 = __hadd2(a1, u2h((unsigned)__shfl_xor((int)h2u(a1), m)));
        a2 = __hadd2(a2, u2h((unsigned)__shfl_xor((int)h2u(a2), m)));
        a3 = __hadd2(a3, u2h((unsigned)__shfl_xor((int)h2u(a3), m)));
    }
    // groups 0/1 write the two float4 halves of the row
    if (g < 2) {
        unsigned w0 = (g == 0) ? u.x : u.z;
        unsigned w1 = (g == 0) ? u.y : u.w;
        float s0 = __low2float(u2h(w0)), s1 = __high2float(u2h(w0));
        float s2 = __low2float(u2h(w1)), s3 = __high2float(u2h(w1));
        __half2 ea = (g == 0) ? a0 : a2;
        __half2 eb = (g == 0) ? a1 : a3;
        float e0 = __low2float(ea), e1 = __high2float(ea);
        float e2 = __low2float(eb), e3 = __high2float(eb);
        float4 o;
        o.x = di * (s0 + e0) + bv.x;
        o.y = di * (s1 + e1) + bv.y;
        o.z = di * (s2 + e2) + bv.z;
        o.w = di * (s3 + e3) + bv.w;
        ((float4*)(out + (size_t)node * C))[l * 2 + g] = o;
    }
}

extern "C" void kernel_launch(void* const* d_in, const int* in_sizes, int n_in,
                              void* d_out, int out_size, void* d_ws, size_t ws_size,
                              hipStream_t stream) {
    const float* x   = (const float*)d_in[0];
    const int*   ei  = (const int*)d_in[1];   // [2, E]: src = ei[e], dst = ei[E+e]
    const float* W   = (const float*)d_in[2];
    const float* b   = (const float*)d_in[3];
    float*       out = (float*)d_out;

    const int N = in_sizes[0] / C;
    const int E = in_sizes[1] / 2;
    const int* src = ei;
    const int* dst = ei + E;

    const int S   = (N + 63) & ~63;   // per-XCD partial stride
    const int nch = (N + 255) >> 8;   // chunks of 256 nodes

    // workspace layout (256B aligned slots)
    char* ws = (char*)d_ws;
    size_t o = 0;
    auto carve = [&](size_t bytes) { char* p = ws + o; o = (o + bytes + 255) & ~(size_t)255; return p; };
    unsigned* part      = (unsigned*)carve((size_t)8 * S * 4);
    unsigned* deg       = (unsigned*)carve((size_t)N * 4);
    unsigned* offs      = (unsigned*)carve((size_t)N * 4);
    unsigned* gctr      = (unsigned*)carve(256);
    float*    dis       = (float*)carve((size_t)N * 4);
    unsigned* rank      = (unsigned*)carve((size_t)E * 4);
    unsigned* ssrc      = (unsigned*)carve((size_t)E * 4);
    unsigned short* hsb = (unsigned short*)carve((size_t)N * C * 2);

    // K1: zero the partial histograms + chunk counter
    int n4 = 2 * S;
    zero_kernel<<<(n4 + 255) / 256, 256, 0, stream>>>((uint4*)part, n4, gctr);

    // K2: per-XCD histogram + packed (xcd, local-rank), 2 edges/thread
    int ng2 = (E + 1) / 2;
    count_part_kernel<<<(ng2 + 255) / 256, 256, 0, stream>>>(dst, part, S, rank, E);

    // K3: fused chunk-scan + gemm (global offs via gctr)
    scan_gemm_kernel<<<nch, 256, 0, stream>>>(part, S, x, W, deg, offs, gctr, dis, hsb, N);

    // K4: bucket
    int ng4 = (E + 3) / 4;
    bucket_kernel<<<(ng4 + 255) / 256, 256, 0, stream>>>(src, dst, offs, part, S, rank, ssrc, E);

    // K5: gather + self loop + bias
    gather_kernel<<<(N + 3) / 4, 256, 0, stream>>>(offs, deg, ssrc, dis, hsb, b, out, N);
}